// Round 11
// baseline (365.633 us; speedup 1.0000x reference)
//
#include <hip/hip_runtime.h>
#include <math.h>

#define VN 9
#define NVOX 131072
#define GS 96
static constexpr float INVS = 0.9999950000374997f; // 1/sqrt(1+1e-5)

typedef short bf16x8 __attribute__((ext_vector_type(8)));
typedef float f32x4v __attribute__((ext_vector_type(4)));

__device__ inline float4 ld4(const float* p){ return *reinterpret_cast<const float4*>(p); }

__device__ inline ushort f2b(float f){
  unsigned u = __float_as_uint(f);
  unsigned r = (u + 0x7fffu + ((u >> 16) & 1u)) >> 16;
  return (ushort)r;
}
__device__ inline float b2f(ushort s){ return __uint_as_float(((unsigned)s) << 16); }
__device__ inline float blo(unsigned u){ return __uint_as_float(u << 16); }
__device__ inline float bhi(unsigned u){ return __uint_as_float(u & 0xffff0000u); }

__device__ inline float4 ld4b(const ushort* p){
  uint2 u = *reinterpret_cast<const uint2*>(p);
  float4 r; r.x = blo(u.x); r.y = bhi(u.x); r.z = blo(u.y); r.w = bhi(u.y); return r;
}
__device__ inline void st4b(ushort* p, float4 v){
  uint2 u;
  u.x = (unsigned)f2b(v.x) | ((unsigned)f2b(v.y) << 16);
  u.y = (unsigned)f2b(v.z) | ((unsigned)f2b(v.w) << 16);
  *reinterpret_cast<uint2*>(p) = u;
}

// ---- weight prep helpers ----
__device__ inline void wprep2_dev(const float* __restrict__ w, ushort* __restrict__ o,
                                  int Cout, int Cin, int K, int CK, int CoutPad, int tid){
  int ci32 = tid & 31;
  int co = (tid >> 5) % CoutPad;
  int ck = (tid / (32*CoutPad)) % CK;
  int tap = tid / (32*CoutPad*CK);
  int ci = ck*32 + ci32;
  float v = 0.f;
  if (co < Cout && ci < Cin) v = w[(size_t)(co*Cin + ci)*K*K + tap];
  o[tid] = f2b(v);
}
__device__ inline void wprep_dev(const float* __restrict__ w, ushort* __restrict__ o, int tid){
  int k = tid >> 10;
  int r = tid & 1023;
  int co = r >> 5;
  int ci = r & 31;
  o[tid] = f2b(w[k*1024 + ci*32 + co]);
}

// ---- NCHW fp32 -> NHWC bf16 via LDS tile ----
__device__ inline void nhwc_tile_dev(const float* __restrict__ in, ushort* __restrict__ out,
                                     int C, int Cpad, int HW, int tile, int tilesPerV,
                                     float* lds, int tx){
  int v  = tile / tilesPerV;
  int p0 = (tile - v*tilesPerV) * 64;
  const float* ip = in + (size_t)v*C*HW + p0;
  int iters = Cpad >> 2;
  for (int i = 0; i < iters; ++i){
    int idx = i*256 + tx;
    int c = idx >> 6;
    int p = idx & 63;
    float val = 0.f;
    if (c < C && (p0 + p) < HW) val = ip[(size_t)c*HW + p];
    lds[c*65 + p] = val;
  }
  __syncthreads();
  int groups = Cpad >> 2;
  int tot = 64*groups;
  for (int basei = 0; basei < tot; basei += 256){
    int idx = basei + tx;
    if (idx < tot){
      int g  = idx % groups;
      int px = idx / groups;
      if ((p0 + px) < HW){
        float4 r;
        r.x = lds[(g*4+0)*65 + px];
        r.y = lds[(g*4+1)*65 + px];
        r.z = lds[(g*4+2)*65 + px];
        r.w = lds[(g*4+3)*65 + px];
        st4b(out + (size_t)(v*HW + p0 + px)*Cpad + g*4, r);
      }
    }
  }
}

// ---- mega prep kernel: weight preps + grid clear + NHWC transposes ----
__global__ __launch_bounds__(256) void k_prep(
    const float* wf1s, const float* wf2s, const float* wf4s, const float* wdns,
    const float* wp0s, const float* wp1s, const float* wp2s, const float* wp3s,
    const float* wes, const float* ws1s, const float* ws2s, const float* ws3s,
    ushort* wf1, ushort* wf2, ushort* wf4, ushort* wdn,
    ushort* wp0, ushort* wp1, ushort* wp2, ushort* wp3,
    ushort* w2e, ushort* w2s1, ushort* w2s2, ushort* w2s3,
    int* grid,
    const float* f1, const float* f2, const float* f4,
    ushort* o1, ushort* o2, ushort* o4){
  __shared__ float lds[96*65];
  int bid = blockIdx.x;
  int tx = threadIdx.x;
  if (bid < 270){ int t = bid*256+tx; if (t < 69120) wprep2_dev(wf1s, wf1, 80, 80, 3, 3, 80, t); return; }
  bid -= 270;
  if (bid < 108){ int t = bid*256+tx; if (t < 27648) wprep2_dev(wf2s, wf2, 40, 40, 3, 2, 48, t); return; }
  bid -= 108;
  if (bid < 36){ int t = bid*256+tx; if (t < 9216) wprep2_dev(wf4s, wf4, 24, 24, 3, 1, 32, t); return; }
  bid -= 36;
  if (bid < 20){ int t = bid*256+tx; if (t < 5120) wprep2_dev(wdns, wdn, 32, 144, 1, 5, 32, t); return; }
  bid -= 20;
  if (bid < 36){ int t = bid*256+tx; if (t < 9216) wprep2_dev(wp0s, wp0, 32, 32, 3, 1, 32, t); return; }
  bid -= 36;
  if (bid < 36){ int t = bid*256+tx; if (t < 9216) wprep2_dev(wp1s, wp1, 32, 32, 3, 1, 32, t); return; }
  bid -= 36;
  if (bid < 36){ int t = bid*256+tx; if (t < 9216) wprep2_dev(wp2s, wp2, 32, 32, 3, 1, 32, t); return; }
  bid -= 36;
  if (bid < 36){ int t = bid*256+tx; if (t < 9216) wprep2_dev(wp3s, wp3, 32, 32, 3, 1, 32, t); return; }
  bid -= 36;
  if (bid < 108){ int t = bid*256+tx; if (t < 27648) wprep_dev(wes, w2e, t); return; }
  bid -= 108;
  if (bid < 108){ int t = bid*256+tx; if (t < 27648) wprep_dev(ws1s, w2s1, t); return; }
  bid -= 108;
  if (bid < 108){ int t = bid*256+tx; if (t < 27648) wprep_dev(ws2s, w2s2, t); return; }
  bid -= 108;
  if (bid < 108){ int t = bid*256+tx; if (t < 27648) wprep_dev(ws3s, w2s3, t); return; }
  bid -= 108;
  if (bid < 3456){ int t = bid*256+tx; if (t < GS*GS*GS) grid[t] = -1; return; }
  bid -= 3456;
  if (bid < 171){ nhwc_tile_dev(f1, o1, 80, 96, 1200, bid, 19, lds, tx); return; }
  bid -= 171;
  if (bid < 675){ nhwc_tile_dev(f2, o2, 40, 64, 4800, bid, 75, lds, tx); return; }
  bid -= 675;
  if (bid < 2700){ nhwc_tile_dev(f4, o4, 24, 32, 19200, bid, 300, lds, tx); }
}

// ---- implicit-GEMM conv via MFMA, register path (f1 / 1x1 down) ----
template<int CK, int NT, int TAPS, int MT>
__device__ void conv_dev(
    const ushort* __restrict__ fin, const ushort* __restrict__ w2,
    const float* __restrict__ bias, ushort* __restrict__ outp,
    int H, int W, int total, int Cout, int outStride, int outOff,
    const ushort* __restrict__ skipin, int bid, int tid){
  constexpr int CIN = CK*32;
  constexpr int COP = NT*16;
  int lane = tid & 63;
  int wave = tid >> 6;
  int vbase = bid*(MT*64) + wave*(MT*16);
  int m = lane & 15, q = lane >> 4;
  int HW = H*W;
  int p[MT], py[MT], px[MT]; bool pin[MT];
  #pragma unroll
  for (int t = 0; t < MT; ++t){
    int pp = vbase + t*16 + m;
    pin[t] = pp < total;
    if (pp > total-1) pp = total-1;
    p[t] = pp;
    int v = pp / HW; int rem = pp - v*HW;
    int y = rem / W;
    py[t] = y; px[t] = rem - y*W;
  }
  f32x4v acc[MT][NT];
  #pragma unroll
  for (int t = 0; t < MT; ++t)
    #pragma unroll
    for (int n = 0; n < NT; ++n) acc[t][n] = 0.f;
  bf16x8 z = (short)0;

  #pragma unroll 1
  for (int tap = 0; tap < TAPS; ++tap){
    int dy = (TAPS == 9) ? tap/3 - 1 : 0;
    int dx = (TAPS == 9) ? tap%3 - 1 : 0;
    int off = dy*W + dx;
    bool val[MT];
    #pragma unroll
    for (int t = 0; t < MT; ++t)
      val[t] = pin[t] && ((unsigned)(py[t]+dy) < (unsigned)H)
                      && ((unsigned)(px[t]+dx) < (unsigned)W);
    #pragma unroll
    for (int ck = 0; ck < CK; ++ck){
      bf16x8 Af[MT], Bf[NT];
      #pragma unroll
      for (int t = 0; t < MT; ++t){
        size_t idx = val[t] ? (size_t)(p[t]+off) : 0;
        bf16x8 a = *(const bf16x8*)(fin + idx*CIN + ck*32 + q*8);
        Af[t] = val[t] ? a : z;
      }
      #pragma unroll
      for (int n = 0; n < NT; ++n)
        Bf[n] = *(const bf16x8*)(w2 + ((size_t)((tap*CK+ck)*COP + n*16 + m))*32 + q*8);
      #pragma unroll
      for (int t = 0; t < MT; ++t)
        #pragma unroll
        for (int n = 0; n < NT; ++n)
          acc[t][n] = __builtin_amdgcn_mfma_f32_16x16x32_bf16(Af[t], Bf[n], acc[t][n], 0, 0, 0);
    }
  }

  #pragma unroll
  for (int n = 0; n < NT; ++n){
    int co = n*16 + m;
    bool cok = co < Cout;
    float bs = cok ? bias[co] : 0.f;
    #pragma unroll
    for (int t = 0; t < MT; ++t){
      #pragma unroll
      for (int r = 0; r < 4; ++r){
        int pp = vbase + t*16 + q*4 + r;
        if (pp < total && cok){
          float x = fmaxf(acc[t][n][r] + bs, 0.f);
          if (skipin) x += b2f(skipin[(size_t)pp*CIN + co]);
          outp[(size_t)pp*outStride + outOff + co] = f2b(x);
        }
      }
    }
  }
}

template<int CK, int NT, int TAPS, int MT>
__global__ __launch_bounds__(256) void k_conv_mfma(
    const ushort* __restrict__ fin, const ushort* __restrict__ w2,
    const float* __restrict__ bias, ushort* __restrict__ outp,
    int H, int W, int total, int Cout, int outStride, int outOff,
    const ushort* __restrict__ skipin){
  conv_dev<CK,NT,TAPS,MT>(fin, w2, bias, outp, H, W, total, Cout, outStride, outOff,
                          skipin, blockIdx.x, threadIdx.x);
}

// ---- LDS-tiled 3x3 conv, CIN=CKI*32. Tile TH x 16 px, halo (TH+2)x18x(CIN+4). ----
template<int TH, int NT, int CKI>
__device__ void conv_lds_dev(
    const ushort* __restrict__ fin, const ushort* __restrict__ w2,
    const float* __restrict__ bias, ushort* __restrict__ outp,
    int H, int W, int Cout, int outStride, int outOff,
    const ushort* __restrict__ skipin, ushort* lds, int bid, int tid){
  constexpr int RPW = TH/4;
  constexpr int CIN = CKI*32;
  constexpr int PS = CIN + 4;
  int xtiles = W >> 4;
  int ytiles = (H + TH - 1) / TH;
  int v  = bid / (ytiles*xtiles);
  int rem = bid - v*(ytiles*xtiles);
  int ty = (rem / xtiles) * TH;
  int tx = (rem % xtiles) * 16;
  const ushort* ibase = fin + (size_t)v*H*W*CIN;
  for (int i = tid; i < (TH+2)*18*(CKI*4); i += 256){
    int chunk = i % (CKI*4);
    int pxi = i / (CKI*4);
    int ly = pxi / 18, lx = pxi - ly*18;
    int gy = ty + ly - 1, gx = tx + lx - 1;
    uint4 d = {0,0,0,0};
    if ((unsigned)gy < (unsigned)H && (unsigned)gx < (unsigned)W)
      d = *(const uint4*)(ibase + ((size_t)gy*W + gx)*CIN + chunk*8);
    *(uint4*)(lds + (size_t)(ly*18 + lx)*PS + chunk*8) = d;
  }
  __syncthreads();
  int lane = tid & 63;
  int wave = tid >> 6;
  int m = lane & 15, q = lane >> 4;
  f32x4v acc[RPW][NT];
  #pragma unroll
  for (int t = 0; t < RPW; ++t)
    #pragma unroll
    for (int n = 0; n < NT; ++n) acc[t][n] = 0.f;

  #pragma unroll 1
  for (int tap = 0; tap < 9; ++tap){
    int dy = tap/3 - 1, dx = tap%3 - 1;
    #pragma unroll
    for (int ck = 0; ck < CKI; ++ck){
      bf16x8 Af[RPW], Bf[NT];
      #pragma unroll
      for (int t = 0; t < RPW; ++t){
        int ly = wave*RPW + t + 1 + dy;
        int lx = m + 1 + dx;
        Af[t] = *(const bf16x8*)(lds + (size_t)(ly*18 + lx)*PS + ck*32 + q*8);
      }
      #pragma unroll
      for (int n = 0; n < NT; ++n)
        Bf[n] = *(const bf16x8*)(w2 + ((size_t)((tap*CKI+ck)*(NT*16) + n*16 + m))*32 + q*8);
      #pragma unroll
      for (int t = 0; t < RPW; ++t)
        #pragma unroll
        for (int n = 0; n < NT; ++n)
          acc[t][n] = __builtin_amdgcn_mfma_f32_16x16x32_bf16(Af[t], Bf[n], acc[t][n], 0, 0, 0);
    }
  }

  #pragma unroll
  for (int n = 0; n < NT; ++n){
    int co = n*16 + m;
    bool cok = co < Cout;
    float bs = cok ? bias[co] : 0.f;
    #pragma unroll
    for (int t = 0; t < RPW; ++t){
      int y = ty + wave*RPW + t;
      #pragma unroll
      for (int r = 0; r < 4; ++r){
        int x = tx + q*4 + r;
        if (y < H && cok){
          size_t pp = (size_t)(v*H + y)*W + x;
          float val = fmaxf(acc[t][n][r] + bs, 0.f);
          if (skipin) val += b2f(skipin[pp*CIN + co]);
          outp[pp*outStride + outOff + co] = f2b(val);
        }
      }
    }
  }
}

// chain conv: TH=4, CIN=32 -> patch 6x18x36 = 7.8 KB, 675 blocks
__global__ __launch_bounds__(256) void k_conv_lds4(
    const ushort* __restrict__ fin, const ushort* __restrict__ w2,
    const float* __restrict__ bias, ushort* __restrict__ outp,
    const ushort* __restrict__ skipin){
  __shared__ ushort lds[6*18*36];
  conv_lds_dev<4,2,1>(fin, w2, bias, outp, 60, 80, 32, 32, 0, skipin, lds, blockIdx.x, threadIdx.x);
}

// ---- standalone scatter (R6-exact projection math — DO NOT inline elsewhere;
//      measured: inlining into k_heads changes contraction and flips boundary masks)
__global__ void k_scatter(const int* __restrict__ coords, const int* __restrict__ stage,
                          int* __restrict__ grid, int* __restrict__ scn,
                          float* __restrict__ coords_out,
                          const float* __restrict__ origin, const float* __restrict__ vsz,
                          const float* __restrict__ KR,
                          uint2* __restrict__ samp, float* __restrict__ cnt){
  int n = blockIdx.x*256 + threadIdx.x;
  if (n >= NVOX) return;
  int c0 = coords[n*4], c1 = coords[n*4+1], c2 = coords[n*4+2], c3 = coords[n*4+3];
  float4 co4; co4.x = (float)c0; co4.y = (float)c1; co4.z = (float)c2; co4.w = (float)c3;
  *reinterpret_cast<float4*>(coords_out + n*4) = co4;
  int sh = 2 - stage[0];
  int s1 = c1 >> sh, s2 = c2 >> sh, s3 = c3 >> sh;
  scn[n*3+0] = s1; scn[n*3+1] = s2; scn[n*3+2] = s3;
  grid[(s1*GS + s2)*GS + s3] = n;

  float vs = vsz[0];
  float wx = (float)c1*vs + origin[0];
  float wy = (float)c2*vs + origin[1];
  float wz = (float)c3*vs + origin[2];
  float den = 0.f;
  #pragma unroll 1
  for (int v = 0; v < VN; ++v){
    const float* P = KR + v*12;
    float ix = P[0]*wx + P[1]*wy + P[2]*wz + P[3];
    float iy = P[4]*wx + P[5]*wy + P[6]*wz + P[7];
    float iz = P[8]*wx + P[9]*wy + P[10]*wz + P[11];
    float rz = 1.f/iz;
    float gx = 2.f*(ix*rz)/159.f - 1.f;
    float gy = 2.f*(iy*rz)/119.f - 1.f;
    bool ok = (fabsf(gx) <= 1.f) && (fabsf(gy) <= 1.f) && (iz > 0.f);
    float px = ok ? (gx + 1.f)*0.5f*79.f : 0.f;
    float py = ok ? (gy + 1.f)*0.5f*59.f : 0.f;
    float x0f = floorf(px), y0f = floorf(py);
    float fx = px - x0f, fy = py - y0f;
    int idx = (int)y0f*80 + (int)x0f;
    float mf = ok ? 1.f : 0.f;
    float w00 = (1.f-fx)*(1.f-fy)*mf, w01 = fx*(1.f-fy)*mf;
    float w10 = (1.f-fx)*fy*mf;
    // packed: .x = idx(13b) | ok<<15 | w10(bf16)<<16 ; .y = w00 | w01<<16
    uint2 s;
    s.x = (unsigned)idx | (ok ? 0x8000u : 0u) | ((unsigned)f2b(w10) << 16);
    s.y = (unsigned)f2b(w00) | ((unsigned)f2b(w01) << 16);
    samp[(size_t)v*NVOX + n] = s;
    den += mf;
  }
  cnt[n] = den;
}

// ---- merged: f1 reg conv (169) + f4 LDS (720) + f2 LDS (675) ----
__global__ __launch_bounds__(256) void k_heads(
    const ushort* nhwc1, const ushort* wf1, const float* b_f1, ushort* t1,
    const ushort* nhwc2, const ushort* wf2, const float* b_f2, ushort* fcat,
    const ushort* nhwc4, const ushort* wf4, const float* b_f4, ushort* t4){
  __shared__ ushort lds[18*18*36];
  int bid = blockIdx.x;
  int tid = threadIdx.x;
  if (bid < 169){ conv_dev<3,5,9,1>(nhwc1, wf1, b_f1, t1, 30, 40, 10800, 80, 80, 0, nullptr, bid, tid); return; }
  bid -= 169;
  if (bid < 720){ conv_lds_dev<16,2,1>(nhwc4, wf4, b_f4, t4, 120, 160, 24, 24, 0, nullptr, lds, bid, tid); return; }
  bid -= 720;
  if (bid < 675){ conv_lds_dev<4,3,2>(nhwc2, wf2, b_f2, fcat, 60, 80, 40, 160, 80, nullptr, lds, bid, tid); }
}

// ---- merged: resize+pool+padzero (5063) + slice-split nbr build (2048) ----
__global__ __launch_bounds__(256) void k_respool_nbr(
    const ushort* __restrict__ t1, const ushort* __restrict__ t4, ushort* __restrict__ fc,
    const int* __restrict__ scn, const int* __restrict__ grid,
    int* __restrict__ nbr, unsigned* __restrict__ gmask16){
  __shared__ unsigned m16[4];
  int bid = blockIdx.x;
  int tidx = threadIdx.x;
  if (bid < 5063){
    int tid = bid*256 + tidx;
    if (tid < 864000){
      int c4 = tid % 20;
      int x  = (tid / 20) % 80;
      int y  = (tid / 1600) % 60;
      int v  = tid / 96000;
      int c = c4*4;
      int ky = y >> 1; int y0, y1; float wy0, wy1;
      if ((y & 1) == 0){ y0 = ky-1; y1 = ky; wy0 = 0.25f; wy1 = 0.75f; if (y0 < 0){ y0 = 0; wy0 = 0.f; wy1 = 1.f; } }
      else             { y0 = ky; y1 = ky+1; wy0 = 0.75f; wy1 = 0.25f; if (y1 > 29){ y1 = 29; wy1 = 0.f; wy0 = 1.f; } }
      int kx = x >> 1; int x0, x1; float wx0, wx1;
      if ((x & 1) == 0){ x0 = kx-1; x1 = kx; wx0 = 0.25f; wx1 = 0.75f; if (x0 < 0){ x0 = 0; wx0 = 0.f; wx1 = 1.f; } }
      else             { x0 = kx; x1 = kx+1; wx0 = 0.75f; wx1 = 0.25f; if (x1 > 39){ x1 = 39; wx1 = 0.f; wx0 = 1.f; } }
      float4 a00 = ld4b(t1 + ((size_t)(v*30 + y0)*40 + x0)*80 + c);
      float4 a01 = ld4b(t1 + ((size_t)(v*30 + y0)*40 + x1)*80 + c);
      float4 a10 = ld4b(t1 + ((size_t)(v*30 + y1)*40 + x0)*80 + c);
      float4 a11 = ld4b(t1 + ((size_t)(v*30 + y1)*40 + x1)*80 + c);
      float w00 = wy0*wx0, w01 = wy0*wx1, w10 = wy1*wx0, w11 = wy1*wx1;
      float4 r;
      r.x = w00*a00.x + w01*a01.x + w10*a10.x + w11*a11.x;
      r.y = w00*a00.y + w01*a01.y + w10*a10.y + w11*a11.y;
      r.z = w00*a00.z + w01*a01.z + w10*a10.z + w11*a11.z;
      r.w = w00*a00.w + w01*a01.w + w10*a10.w + w11*a11.w;
      st4b(fc + ((size_t)(v*60 + y)*80 + x)*160 + c, r);
      return;
    }
    int t = tid - 864000;
    if (t >= 432000) return;
    int c4 = t % 10;
    int x  = (t / 10) % 80;
    int y  = (t / 800) % 60;
    int v  = t / 48000;
    if (c4 < 6){
      int c = c4*4;
      const ushort* b0 = t4 + ((size_t)(v*120 + 2*y)*160 + 2*x)*24 + c;
      float4 a = ld4b(b0), b = ld4b(b0 + 24), cc = ld4b(b0 + 160*24), d = ld4b(b0 + 160*24 + 24);
      float4 r;
      r.x = 0.25f*(a.x + b.x + cc.x + d.x);
      r.y = 0.25f*(a.y + b.y + cc.y + d.y);
      r.z = 0.25f*(a.z + b.z + cc.z + d.z);
      r.w = 0.25f*(a.w + b.w + cc.w + d.w);
      st4b(fc + ((size_t)(v*60 + y)*80 + x)*160 + 120 + c, r);
    } else {
      float4 zz = {0.f,0.f,0.f,0.f};
      st4b(fc + ((size_t)(v*60 + y)*80 + x)*160 + 144 + (c4-6)*4, zz);
    }
    return;
  }
  bid -= 5063;
  if (tidx < 4) m16[tidx] = 0;
  __syncthreads();
  int vb = bid*64;
  int lane = tidx & 63;
  int wv = tidx >> 6;
  int n = vb + lane;
  int sx = scn[n*3+0], sy = scn[n*3+1], sz = scn[n*3+2];
  int k0 = wv*7;
  int k1 = min(27, k0 + 7);
  unsigned msk = 0;
  #pragma unroll 1
  for (int k = k0; k < k1; ++k){
    int dx = k/9 - 1, dy = (k/3)%3 - 1, dz = k%3 - 1;
    int nx = sx+dx, ny = sy+dy, nz = sz+dz;
    int idx = -1;
    if (((unsigned)nx < 96u) && ((unsigned)ny < 96u) && ((unsigned)nz < 96u))
      idx = grid[(nx*GS + ny)*GS + nz];
    nbr[(size_t)k*NVOX + n] = idx;
    unsigned long long b = __ballot(idx >= 0);
    unsigned sub = (unsigned)((b >> ((lane >> 4)*16)) & 0xFFFFull);
    if (sub) msk |= (1u << k);
  }
  if ((lane & 15) == 0 && msk) atomicOr(&m16[lane >> 4], msk);
  __syncthreads();
  if (tidx < 4) gmask16[(vb >> 4) + tidx] = m16[tidx];
}

// ---- sampling from packed table + masked mean/var + bn0 ----
__global__ __launch_bounds__(256) void k_sample(
    const ushort* __restrict__ fuse, const uint2* __restrict__ samp,
    const float* __restrict__ cnt, const float* __restrict__ bn0g,
    const float* __restrict__ bn0b, ushort* __restrict__ F0){
  int tid = blockIdx.x*256 + threadIdx.x;
  int vox = tid >> 3;
  int c4 = tid & 7;
  int c = c4*4;
  uint2 svv[VN];
  #pragma unroll
  for (int v = 0; v < VN; ++v) svv[v] = samp[(size_t)v*NVOX + vox];
  float s0=0.f,s1=0.f,s2=0.f,s3=0.f;
  float q0=0.f,q1=0.f,q2=0.f,q3=0.f;
  #pragma unroll
  for (int v = 0; v < VN; ++v){
    uint2 sv = svv[v];
    int idx = (int)(sv.x & 0x7FFFu);
    float mf = (sv.x & 0x8000u) ? 1.f : 0.f;
    float w10 = bhi(sv.x);
    float w00 = blo(sv.y), w01 = bhi(sv.y);
    float w11 = mf - w00 - w01 - w10;
    const ushort* bp = fuse + (size_t)v*153600 + (size_t)idx*32 + c;
    float4 a00 = ld4b(bp);
    float4 a01 = ld4b(bp + 32);
    float4 a10 = ld4b(bp + 2560);
    float4 a11 = ld4b(bp + 2592);
    float g0 = w00*a00.x + w01*a01.x + w10*a10.x + w11*a11.x;
    float g1 = w00*a00.y + w01*a01.y + w10*a10.y + w11*a11.y;
    float g2 = w00*a00.z + w01*a01.z + w10*a10.z + w11*a11.z;
    float g3 = w00*a00.w + w01*a01.w + w10*a10.w + w11*a11.w;
    s0 += g0; q0 += g0*g0;
    s1 += g1; q1 += g1*g1;
    s2 += g2; q2 += g2*g2;
    s3 += g3; q3 += g3*g3;
  }
  float iden = 1.f/cnt[vox];
  float m0 = s0*iden, m1 = s1*iden, m2 = s2*iden, m3 = s3*iden;
  float4 g = ld4(bn0g + c);
  float4 b = ld4(bn0b + c);
  float4 r;
  r.x = g.x*fmaxf(q0*iden - m0*m0, 0.f)*INVS + b.x;
  r.y = g.y*fmaxf(q1*iden - m1*m1, 0.f)*INVS + b.y;
  r.z = g.z*fmaxf(q2*iden - m2*m2, 0.f)*INVS + b.z;
  r.w = g.w*fmaxf(q3*iden - m3*m3, 0.f)*INVS + b.w;
  st4b(F0 + (size_t)vox*32 + c, r);
}

// ---- subm sparse conv 32->32, 16 vox/wave, 3-deep id + 2-deep A pipeline ----
template<int MODE>
__global__ __launch_bounds__(256, 8) void k_subm_mfma(
    const ushort* __restrict__ fin, const ushort* __restrict__ w2,
    const int* __restrict__ nbr, const unsigned* __restrict__ gmask16,
    const float* __restrict__ lng, const float* __restrict__ lnb,
    ushort* __restrict__ fout){
  int lane = threadIdx.x & 63;
  int wave = threadIdx.x >> 6;
  int vb = blockIdx.x*64 + wave*16;
  int m = lane & 15;
  int q = lane >> 4;

  f32x4v acc0 = 0.f, acc1 = 0.f;
  bf16x8 zc = (short)0;
  unsigned rem = gmask16[vb >> 4];
  // k0: current MFMA slice; q0 = id for k1 (next gather); q1 = id for k2
  int k0 = -1, k1 = -1, k2 = -1;
  int ida = -1, q0 = -1, q1 = -1;
  if (rem){ k0 = __ffs(rem) - 1; rem &= rem - 1; ida = nbr[(size_t)k0*NVOX + vb + m]; }
  if (rem){ k1 = __ffs(rem) - 1; rem &= rem - 1; q0 = nbr[(size_t)k1*NVOX + vb + m]; }
  if (rem){ k2 = __ffs(rem) - 1; rem &= rem - 1; q1 = nbr[(size_t)k2*NVOX + vb + m]; }
  bf16x8 A0 = zc;
  if (k0 >= 0){
    bf16x8 a = *(const bf16x8*)(fin + (size_t)(ida < 0 ? 0 : ida)*32 + q*8);
    A0 = (ida < 0) ? zc : a;
  }
  while (k0 >= 0){
    // gather A for k1; fetch id for k3
    bf16x8 A1 = zc;
    if (k1 >= 0){
      bf16x8 a = *(const bf16x8*)(fin + (size_t)(q0 < 0 ? 0 : q0)*32 + q*8);
      A1 = (q0 < 0) ? zc : a;
    }
    int k3 = -1, qn = -1;
    if (rem){ k3 = __ffs(rem) - 1; rem &= rem - 1; qn = nbr[(size_t)k3*NVOX + vb + m]; }
    bf16x8 b0 = *(const bf16x8*)(w2 + (size_t)(k0*32 + m)*32 + q*8);
    bf16x8 b1 = *(const bf16x8*)(w2 + (size_t)(k0*32 + 16 + m)*32 + q*8);
    acc0 = __builtin_amdgcn_mfma_f32_16x16x32_bf16(A0, b0, acc0, 0, 0, 0);
    acc1 = __builtin_amdgcn_mfma_f32_16x16x32_bf16(A0, b1, acc1, 0, 0, 0);
    A0 = A1; q0 = q1; q1 = qn;
    k0 = k1; k1 = k2; k2 = k3;
  }

  int ch0 = m, ch1 = 16 + m;
  float g0 = 0.f, g1 = 0.f, bb0 = 0.f, bb1 = 0.f;
  if (MODE == 1){ g0 = lng[ch0]; g1 = lng[ch1]; bb0 = lnb[ch0]; bb1 = lnb[ch1]; }
  #pragma unroll
  for (int r = 0; r < 4; ++r){
    int vox = vb + q*4 + r;
    float x0 = fmaxf(acc0[r], 0.f);
    float x1 = fmaxf(acc1[r], 0.f);
    if (MODE == 1){
      x0 += b2f(fin[(size_t)vox*32 + ch0]);
      x1 += b2f(fin[(size_t)vox*32 + ch1]);
      float s = x0 + x1;
      s += __shfl_xor(s, 1, 16);
      s += __shfl_xor(s, 2, 16);
      s += __shfl_xor(s, 4, 16);
      s += __shfl_xor(s, 8, 16);
      float mean = s * (1.f/32.f);
      float d0 = x0 - mean, d1 = x1 - mean;
      float v2 = d0*d0 + d1*d1;
      v2 += __shfl_xor(v2, 1, 16);
      v2 += __shfl_xor(v2, 2, 16);
      v2 += __shfl_xor(v2, 4, 16);
      v2 += __shfl_xor(v2, 8, 16);
      float rs = 1.f / sqrtf(v2*(1.f/32.f) + 1e-5f);
      x0 = d0*rs*g0 + bb0;
      x1 = d1*rs*g1 + bb1;
    }
    fout[(size_t)vox*32 + ch0] = f2b(x0);
    fout[(size_t)vox*32 + ch1] = f2b(x1);
  }
}

// ---- final subm 32->1 + bn, idx prefetch ----
__global__ __launch_bounds__(256) void k_s4(
    const ushort* __restrict__ fin, const float* __restrict__ w4,
    const int* __restrict__ nbr, const unsigned* __restrict__ gmask16,
    const float* __restrict__ bn4g, const float* __restrict__ bn4b,
    float* __restrict__ occ){
  int n = blockIdx.x*256 + threadIdx.x;
  if (n >= NVOX) return;
  unsigned rem = gmask16[n >> 4];
  float acc = 0.f;
  int k = -1, idx = -1;
  if (rem){ k = __ffs(rem) - 1; rem &= rem - 1; idx = nbr[(size_t)k*NVOX + n]; }
  while (k >= 0){
    int k2 = -1, idx2 = -1;
    if (rem){ k2 = __ffs(rem) - 1; rem &= rem - 1; idx2 = nbr[(size_t)k2*NVOX + n]; }
    if (idx >= 0){
      const uint4* r4 = (const uint4*)(fin + (size_t)idx*32);
      const float* wk = w4 + k*32;
      #pragma unroll
      for (int u = 0; u < 4; ++u){
        uint4 d = r4[u];
        const float* w8 = wk + u*8;
        acc += blo(d.x)*w8[0] + bhi(d.x)*w8[1];
        acc += blo(d.y)*w8[2] + bhi(d.y)*w8[3];
        acc += blo(d.z)*w8[4] + bhi(d.z)*w8[5];
        acc += blo(d.w)*w8[6] + bhi(d.w)*w8[7];
      }
    }
    k = k2; idx = idx2;
  }
  occ[n] = bn4g[0]*acc*INVS + bn4b[0];
}

extern "C" void kernel_launch(void* const* d_in, const int* in_sizes, int n_in,
                              void* d_out, int out_size, void* d_ws, size_t ws_size,
                              hipStream_t stream){
  const float* feats1 = (const float*)d_in[0];
  const float* feats2 = (const float*)d_in[1];
  const float* feats4 = (const float*)d_in[2];
  const int*   coords = (const int*)d_in[3];
  const float* origin = (const float*)d_in[4];
  const float* vsz    = (const float*)d_in[5];
  const float* KR     = (const float*)d_in[6];
  const float* w_f1 = (const float*)d_in[7];  const float* b_f1 = (const float*)d_in[8];
  const float* w_f2 = (const float*)d_in[9];  const float* b_f2 = (const float*)d_in[10];
  const float* w_f4 = (const float*)d_in[11]; const float* b_f4 = (const float*)d_in[12];
  const float* w_dn = (const float*)d_in[13]; const float* b_dn = (const float*)d_in[14];
  const float* w_p[4] = {(const float*)d_in[15], (const float*)d_in[17],
                         (const float*)d_in[19], (const float*)d_in[21]};
  const float* b_p[4] = {(const float*)d_in[16], (const float*)d_in[18],
                         (const float*)d_in[20], (const float*)d_in[22]};
  const float* bn0g = (const float*)d_in[23]; const float* bn0b = (const float*)d_in[24];
  const float* w_elan = (const float*)d_in[25];
  const float* w_s1 = (const float*)d_in[26]; const float* ln1g = (const float*)d_in[27]; const float* ln1b = (const float*)d_in[28];
  const float* w_s2 = (const float*)d_in[29]; const float* ln2g = (const float*)d_in[30]; const float* ln2b = (const float*)d_in[31];
  const float* w_s3 = (const float*)d_in[32]; const float* ln3g = (const float*)d_in[33]; const float* ln3b = (const float*)d_in[34];
  const float* w_s4 = (const float*)d_in[35]; const float* bn4g = (const float*)d_in[36]; const float* bn4b = (const float*)d_in[37];
  const int* stage  = (const int*)d_in[38];
  float* out = (float*)d_out;
  char* base = (char*)d_ws;

  size_t off = 0;
  auto alloc = [&](size_t bytes)->char*{ char* p = base + off; off += (bytes + 255) & ~(size_t)255; return p; };
  ushort* nhwc1 = (ushort*)alloc((size_t)9*30*40*96*2);
  ushort* nhwc2 = (ushort*)alloc((size_t)9*60*80*64*2);
  ushort* nhwc4 = (ushort*)alloc((size_t)9*120*160*32*2);
  ushort* t1    = (ushort*)alloc((size_t)9*30*40*80*2);
  ushort* t4    = (ushort*)alloc((size_t)9*120*160*24*2);
  ushort* fcat  = (ushort*)alloc((size_t)9*60*80*160*2);
  ushort* A     = (ushort*)alloc((size_t)9*60*80*32*2);
  ushort* B     = (ushort*)alloc((size_t)9*60*80*32*2);
  ushort* Fb0   = (ushort*)alloc((size_t)NVOX*32*2);
  ushort* Fb1   = (ushort*)alloc((size_t)NVOX*32*2);
  int*    nbr   = (int*)alloc((size_t)27*NVOX*4);
  int*    grid  = (int*)alloc((size_t)GS*GS*GS*4);
  int*    scn   = (int*)alloc((size_t)NVOX*3*4);
  unsigned* gmask16 = (unsigned*)alloc((size_t)(NVOX/16)*4);
  ushort* wf1   = (ushort*)alloc(9*3*80*32*2);
  ushort* wf2   = (ushort*)alloc(9*2*48*32*2);
  ushort* wf4   = (ushort*)alloc(9*1*32*32*2);
  ushort* wdn   = (ushort*)alloc(1*5*32*32*2);
  ushort* wp0   = (ushort*)alloc(9*1*32*32*2);
  ushort* wp1   = (ushort*)alloc(9*1*32*32*2);
  ushort* wp2   = (ushort*)alloc(9*1*32*32*2);
  ushort* wp3   = (ushort*)alloc(9*1*32*32*2);
  ushort* w2e   = (ushort*)alloc(27*1024*2);
  ushort* w2s1  = (ushort*)alloc(27*1024*2);
  ushort* w2s2  = (ushort*)alloc(27*1024*2);
  ushort* w2s3  = (ushort*)alloc(27*1024*2);
  uint2* samp = (uint2*)alloc((size_t)VN*NVOX*8);  // packed, 9.4 MB

  auto nb = [](int total){ return (total + 255)/256; };

  // 1. mega prep
  k_prep<<<8012,256,0,stream>>>(
      w_f1, w_f2, w_f4, w_dn, w_p[0], w_p[1], w_p[2], w_p[3],
      w_elan, w_s1, w_s2, w_s3,
      wf1, wf2, wf4, wdn, wp0, wp1, wp2, wp3, w2e, w2s1, w2s2, w2s3, grid,
      feats1, feats2, feats4, nhwc1, nhwc2, nhwc4);

  // 2. standalone scatter (R6-exact codegen; measured flip-free)
  k_scatter<<<nb(NVOX),256,0,stream>>>(coords, stage, grid, scn, out + NVOX,
                                       origin, vsz, KR, samp, out + 5*NVOX);

  // 3. head convs (f1 reg, f4 LDS, f2 LDS)
  k_heads<<<169 + 720 + 675,256,0,stream>>>(
      nhwc1, wf1, b_f1, t1,
      nhwc2, wf2, b_f2, fcat,
      nhwc4, wf4, b_f4, t4);

  // 4. respool + nbr build
  k_respool_nbr<<<5063 + 2048,256,0,stream>>>(t1, t4, fcat, scn, grid, nbr, gmask16);

  // 5-9. down conv (1x1 reg) + 4 LDS-tiled residual convs
  k_conv_mfma<5,2,1,1><<<675,256,0,stream>>>(fcat, wdn, b_dn, A, 60, 80, 43200, 32, 32, 0, nullptr);
  k_conv_lds4<<<675,256,0,stream>>>(A, wp0, b_p[0], B, A);
  k_conv_lds4<<<675,256,0,stream>>>(B, wp1, b_p[1], A, B);
  k_conv_lds4<<<675,256,0,stream>>>(A, wp2, b_p[2], B, A);
  k_conv_lds4<<<675,256,0,stream>>>(B, wp3, b_p[3], A, B);

  // 10. sampling -> F0
  k_sample<<<NVOX/32,256,0,stream>>>(A, samp, out + 5*NVOX, bn0g, bn0b, Fb0);

  // 11-14. sparse conv stack
  k_subm_mfma<0><<<NVOX/64,256,0,stream>>>(Fb0, w2e,  nbr, gmask16, nullptr, nullptr, Fb1);
  k_subm_mfma<1><<<NVOX/64,256,0,stream>>>(Fb1, w2s1, nbr, gmask16, ln1g, ln1b, Fb0);
  k_subm_mfma<1><<<NVOX/64,256,0,stream>>>(Fb0, w2s2, nbr, gmask16, ln2g, ln2b, Fb1);
  k_subm_mfma<1><<<NVOX/64,256,0,stream>>>(Fb1, w2s3, nbr, gmask16, ln3g, ln3b, Fb0);

  // 15. final head
  k_s4<<<nb(NVOX),256,0,stream>>>(Fb0, w_s4, nbr, gmask16, bn4g, bn4b, out);
}

// Round 12
// 353.759 us; speedup vs baseline: 1.0336x; 1.0336x over previous
//
#include <hip/hip_runtime.h>
#include <math.h>

#define VN 9
#define NVOX 131072
#define GS 96
static constexpr float INVS = 0.9999950000374997f; // 1/sqrt(1+1e-5)

typedef short bf16x8 __attribute__((ext_vector_type(8)));
typedef float f32x4v __attribute__((ext_vector_type(4)));

__device__ inline float4 ld4(const float* p){ return *reinterpret_cast<const float4*>(p); }

__device__ inline ushort f2b(float f){
  unsigned u = __float_as_uint(f);
  unsigned r = (u + 0x7fffu + ((u >> 16) & 1u)) >> 16;
  return (ushort)r;
}
__device__ inline float b2f(ushort s){ return __uint_as_float(((unsigned)s) << 16); }
__device__ inline float blo(unsigned u){ return __uint_as_float(u << 16); }
__device__ inline float bhi(unsigned u){ return __uint_as_float(u & 0xffff0000u); }

__device__ inline float4 ld4b(const ushort* p){
  uint2 u = *reinterpret_cast<const uint2*>(p);
  float4 r; r.x = blo(u.x); r.y = bhi(u.x); r.z = blo(u.y); r.w = bhi(u.y); return r;
}
__device__ inline void st4b(ushort* p, float4 v){
  uint2 u;
  u.x = (unsigned)f2b(v.x) | ((unsigned)f2b(v.y) << 16);
  u.y = (unsigned)f2b(v.z) | ((unsigned)f2b(v.w) << 16);
  *reinterpret_cast<uint2*>(p) = u;
}

// ---- weight prep helpers ----
__device__ inline void wprep2_dev(const float* __restrict__ w, ushort* __restrict__ o,
                                  int Cout, int Cin, int K, int CK, int CoutPad, int tid){
  int ci32 = tid & 31;
  int co = (tid >> 5) % CoutPad;
  int ck = (tid / (32*CoutPad)) % CK;
  int tap = tid / (32*CoutPad*CK);
  int ci = ck*32 + ci32;
  float v = 0.f;
  if (co < Cout && ci < Cin) v = w[(size_t)(co*Cin + ci)*K*K + tap];
  o[tid] = f2b(v);
}
__device__ inline void wprep_dev(const float* __restrict__ w, ushort* __restrict__ o, int tid){
  int k = tid >> 10;
  int r = tid & 1023;
  int co = r >> 5;
  int ci = r & 31;
  o[tid] = f2b(w[k*1024 + ci*32 + co]);
}

// ---- NCHW fp32 -> NHWC bf16 via LDS tile ----
__device__ inline void nhwc_tile_dev(const float* __restrict__ in, ushort* __restrict__ out,
                                     int C, int Cpad, int HW, int tile, int tilesPerV,
                                     float* lds, int tx){
  int v  = tile / tilesPerV;
  int p0 = (tile - v*tilesPerV) * 64;
  const float* ip = in + (size_t)v*C*HW + p0;
  int iters = Cpad >> 2;
  for (int i = 0; i < iters; ++i){
    int idx = i*256 + tx;
    int c = idx >> 6;
    int p = idx & 63;
    float val = 0.f;
    if (c < C && (p0 + p) < HW) val = ip[(size_t)c*HW + p];
    lds[c*65 + p] = val;
  }
  __syncthreads();
  int groups = Cpad >> 2;
  int tot = 64*groups;
  for (int basei = 0; basei < tot; basei += 256){
    int idx = basei + tx;
    if (idx < tot){
      int g  = idx % groups;
      int px = idx / groups;
      if ((p0 + px) < HW){
        float4 r;
        r.x = lds[(g*4+0)*65 + px];
        r.y = lds[(g*4+1)*65 + px];
        r.z = lds[(g*4+2)*65 + px];
        r.w = lds[(g*4+3)*65 + px];
        st4b(out + (size_t)(v*HW + p0 + px)*Cpad + g*4, r);
      }
    }
  }
}

// ---- mega prep kernel: weight preps + grid clear + NHWC transposes ----
__global__ __launch_bounds__(256) void k_prep(
    const float* wf1s, const float* wf2s, const float* wf4s, const float* wdns,
    const float* wp0s, const float* wp1s, const float* wp2s, const float* wp3s,
    const float* wes, const float* ws1s, const float* ws2s, const float* ws3s,
    ushort* wf1, ushort* wf2, ushort* wf4, ushort* wdn,
    ushort* wp0, ushort* wp1, ushort* wp2, ushort* wp3,
    ushort* w2e, ushort* w2s1, ushort* w2s2, ushort* w2s3,
    int* grid,
    const float* f1, const float* f2, const float* f4,
    ushort* o1, ushort* o2, ushort* o4){
  __shared__ float lds[96*65];
  int bid = blockIdx.x;
  int tx = threadIdx.x;
  if (bid < 270){ int t = bid*256+tx; if (t < 69120) wprep2_dev(wf1s, wf1, 80, 80, 3, 3, 80, t); return; }
  bid -= 270;
  if (bid < 108){ int t = bid*256+tx; if (t < 27648) wprep2_dev(wf2s, wf2, 40, 40, 3, 2, 48, t); return; }
  bid -= 108;
  if (bid < 36){ int t = bid*256+tx; if (t < 9216) wprep2_dev(wf4s, wf4, 24, 24, 3, 1, 32, t); return; }
  bid -= 36;
  if (bid < 20){ int t = bid*256+tx; if (t < 5120) wprep2_dev(wdns, wdn, 32, 144, 1, 5, 32, t); return; }
  bid -= 20;
  if (bid < 36){ int t = bid*256+tx; if (t < 9216) wprep2_dev(wp0s, wp0, 32, 32, 3, 1, 32, t); return; }
  bid -= 36;
  if (bid < 36){ int t = bid*256+tx; if (t < 9216) wprep2_dev(wp1s, wp1, 32, 32, 3, 1, 32, t); return; }
  bid -= 36;
  if (bid < 36){ int t = bid*256+tx; if (t < 9216) wprep2_dev(wp2s, wp2, 32, 32, 3, 1, 32, t); return; }
  bid -= 36;
  if (bid < 36){ int t = bid*256+tx; if (t < 9216) wprep2_dev(wp3s, wp3, 32, 32, 3, 1, 32, t); return; }
  bid -= 36;
  if (bid < 108){ int t = bid*256+tx; if (t < 27648) wprep_dev(wes, w2e, t); return; }
  bid -= 108;
  if (bid < 108){ int t = bid*256+tx; if (t < 27648) wprep_dev(ws1s, w2s1, t); return; }
  bid -= 108;
  if (bid < 108){ int t = bid*256+tx; if (t < 27648) wprep_dev(ws2s, w2s2, t); return; }
  bid -= 108;
  if (bid < 108){ int t = bid*256+tx; if (t < 27648) wprep_dev(ws3s, w2s3, t); return; }
  bid -= 108;
  if (bid < 3456){ int t = bid*256+tx; if (t < GS*GS*GS) grid[t] = -1; return; }
  bid -= 3456;
  if (bid < 171){ nhwc_tile_dev(f1, o1, 80, 96, 1200, bid, 19, lds, tx); return; }
  bid -= 171;
  if (bid < 675){ nhwc_tile_dev(f2, o2, 40, 64, 4800, bid, 75, lds, tx); return; }
  bid -= 675;
  if (bid < 2700){ nhwc_tile_dev(f4, o4, 24, 32, 19200, bid, 300, lds, tx); }
}

// ---- implicit-GEMM conv via MFMA, register path (f1 / 1x1 down) ----
template<int CK, int NT, int TAPS, int MT>
__device__ void conv_dev(
    const ushort* __restrict__ fin, const ushort* __restrict__ w2,
    const float* __restrict__ bias, ushort* __restrict__ outp,
    int H, int W, int total, int Cout, int outStride, int outOff,
    const ushort* __restrict__ skipin, int bid, int tid){
  constexpr int CIN = CK*32;
  constexpr int COP = NT*16;
  int lane = tid & 63;
  int wave = tid >> 6;
  int vbase = bid*(MT*64) + wave*(MT*16);
  int m = lane & 15, q = lane >> 4;
  int HW = H*W;
  int p[MT], py[MT], px[MT]; bool pin[MT];
  #pragma unroll
  for (int t = 0; t < MT; ++t){
    int pp = vbase + t*16 + m;
    pin[t] = pp < total;
    if (pp > total-1) pp = total-1;
    p[t] = pp;
    int v = pp / HW; int rem = pp - v*HW;
    int y = rem / W;
    py[t] = y; px[t] = rem - y*W;
  }
  f32x4v acc[MT][NT];
  #pragma unroll
  for (int t = 0; t < MT; ++t)
    #pragma unroll
    for (int n = 0; n < NT; ++n) acc[t][n] = 0.f;
  bf16x8 z = (short)0;

  #pragma unroll 1
  for (int tap = 0; tap < TAPS; ++tap){
    int dy = (TAPS == 9) ? tap/3 - 1 : 0;
    int dx = (TAPS == 9) ? tap%3 - 1 : 0;
    int off = dy*W + dx;
    bool val[MT];
    #pragma unroll
    for (int t = 0; t < MT; ++t)
      val[t] = pin[t] && ((unsigned)(py[t]+dy) < (unsigned)H)
                      && ((unsigned)(px[t]+dx) < (unsigned)W);
    #pragma unroll
    for (int ck = 0; ck < CK; ++ck){
      bf16x8 Af[MT], Bf[NT];
      #pragma unroll
      for (int t = 0; t < MT; ++t){
        size_t idx = val[t] ? (size_t)(p[t]+off) : 0;
        bf16x8 a = *(const bf16x8*)(fin + idx*CIN + ck*32 + q*8);
        Af[t] = val[t] ? a : z;
      }
      #pragma unroll
      for (int n = 0; n < NT; ++n)
        Bf[n] = *(const bf16x8*)(w2 + ((size_t)((tap*CK+ck)*COP + n*16 + m))*32 + q*8);
      #pragma unroll
      for (int t = 0; t < MT; ++t)
        #pragma unroll
        for (int n = 0; n < NT; ++n)
          acc[t][n] = __builtin_amdgcn_mfma_f32_16x16x32_bf16(Af[t], Bf[n], acc[t][n], 0, 0, 0);
    }
  }

  #pragma unroll
  for (int n = 0; n < NT; ++n){
    int co = n*16 + m;
    bool cok = co < Cout;
    float bs = cok ? bias[co] : 0.f;
    #pragma unroll
    for (int t = 0; t < MT; ++t){
      #pragma unroll
      for (int r = 0; r < 4; ++r){
        int pp = vbase + t*16 + q*4 + r;
        if (pp < total && cok){
          float x = fmaxf(acc[t][n][r] + bs, 0.f);
          if (skipin) x += b2f(skipin[(size_t)pp*CIN + co]);
          outp[(size_t)pp*outStride + outOff + co] = f2b(x);
        }
      }
    }
  }
}

template<int CK, int NT, int TAPS, int MT>
__global__ __launch_bounds__(256) void k_conv_mfma(
    const ushort* __restrict__ fin, const ushort* __restrict__ w2,
    const float* __restrict__ bias, ushort* __restrict__ outp,
    int H, int W, int total, int Cout, int outStride, int outOff,
    const ushort* __restrict__ skipin){
  conv_dev<CK,NT,TAPS,MT>(fin, w2, bias, outp, H, W, total, Cout, outStride, outOff,
                          skipin, blockIdx.x, threadIdx.x);
}

// ---- LDS-tiled 3x3 conv, CIN=CKI*32. Tile TH x 16 px, halo (TH+2)x18x(CIN+4). ----
template<int TH, int NT, int CKI>
__device__ void conv_lds_dev(
    const ushort* __restrict__ fin, const ushort* __restrict__ w2,
    const float* __restrict__ bias, ushort* __restrict__ outp,
    int H, int W, int Cout, int outStride, int outOff,
    const ushort* __restrict__ skipin, ushort* lds, int bid, int tid){
  constexpr int RPW = TH/4;
  constexpr int CIN = CKI*32;
  constexpr int PS = CIN + 4;
  int xtiles = W >> 4;
  int ytiles = (H + TH - 1) / TH;
  int v  = bid / (ytiles*xtiles);
  int rem = bid - v*(ytiles*xtiles);
  int ty = (rem / xtiles) * TH;
  int tx = (rem % xtiles) * 16;
  const ushort* ibase = fin + (size_t)v*H*W*CIN;
  for (int i = tid; i < (TH+2)*18*(CKI*4); i += 256){
    int chunk = i % (CKI*4);
    int pxi = i / (CKI*4);
    int ly = pxi / 18, lx = pxi - ly*18;
    int gy = ty + ly - 1, gx = tx + lx - 1;
    uint4 d = {0,0,0,0};
    if ((unsigned)gy < (unsigned)H && (unsigned)gx < (unsigned)W)
      d = *(const uint4*)(ibase + ((size_t)gy*W + gx)*CIN + chunk*8);
    *(uint4*)(lds + (size_t)(ly*18 + lx)*PS + chunk*8) = d;
  }
  __syncthreads();
  int lane = tid & 63;
  int wave = tid >> 6;
  int m = lane & 15, q = lane >> 4;
  f32x4v acc[RPW][NT];
  #pragma unroll
  for (int t = 0; t < RPW; ++t)
    #pragma unroll
    for (int n = 0; n < NT; ++n) acc[t][n] = 0.f;

  #pragma unroll 1
  for (int tap = 0; tap < 9; ++tap){
    int dy = tap/3 - 1, dx = tap%3 - 1;
    #pragma unroll
    for (int ck = 0; ck < CKI; ++ck){
      bf16x8 Af[RPW], Bf[NT];
      #pragma unroll
      for (int t = 0; t < RPW; ++t){
        int ly = wave*RPW + t + 1 + dy;
        int lx = m + 1 + dx;
        Af[t] = *(const bf16x8*)(lds + (size_t)(ly*18 + lx)*PS + ck*32 + q*8);
      }
      #pragma unroll
      for (int n = 0; n < NT; ++n)
        Bf[n] = *(const bf16x8*)(w2 + ((size_t)((tap*CKI+ck)*(NT*16) + n*16 + m))*32 + q*8);
      #pragma unroll
      for (int t = 0; t < RPW; ++t)
        #pragma unroll
        for (int n = 0; n < NT; ++n)
          acc[t][n] = __builtin_amdgcn_mfma_f32_16x16x32_bf16(Af[t], Bf[n], acc[t][n], 0, 0, 0);
    }
  }

  #pragma unroll
  for (int n = 0; n < NT; ++n){
    int co = n*16 + m;
    bool cok = co < Cout;
    float bs = cok ? bias[co] : 0.f;
    #pragma unroll
    for (int t = 0; t < RPW; ++t){
      int y = ty + wave*RPW + t;
      #pragma unroll
      for (int r = 0; r < 4; ++r){
        int x = tx + q*4 + r;
        if (y < H && cok){
          size_t pp = (size_t)(v*H + y)*W + x;
          float val = fmaxf(acc[t][n][r] + bs, 0.f);
          if (skipin) val += b2f(skipin[pp*CIN + co]);
          outp[pp*outStride + outOff + co] = f2b(val);
        }
      }
    }
  }
}

// chain conv: TH=4, CIN=32 -> patch 6x18x36 = 7.8 KB, 675 blocks
__global__ __launch_bounds__(256) void k_conv_lds4(
    const ushort* __restrict__ fin, const ushort* __restrict__ w2,
    const float* __restrict__ bias, ushort* __restrict__ outp,
    const ushort* __restrict__ skipin){
  __shared__ ushort lds[6*18*36];
  conv_lds_dev<4,2,1>(fin, w2, bias, outp, 60, 80, 32, 32, 0, skipin, lds, blockIdx.x, threadIdx.x);
}

// ---- standalone scatter (R6-exact projection math — DO NOT inline elsewhere;
//      measured: inlining into k_heads changes contraction and flips boundary masks)
__global__ void k_scatter(const int* __restrict__ coords, const int* __restrict__ stage,
                          int* __restrict__ grid, int* __restrict__ scn,
                          float* __restrict__ coords_out,
                          const float* __restrict__ origin, const float* __restrict__ vsz,
                          const float* __restrict__ KR,
                          uint2* __restrict__ samp, float* __restrict__ cnt){
  int n = blockIdx.x*256 + threadIdx.x;
  if (n >= NVOX) return;
  int c0 = coords[n*4], c1 = coords[n*4+1], c2 = coords[n*4+2], c3 = coords[n*4+3];
  float4 co4; co4.x = (float)c0; co4.y = (float)c1; co4.z = (float)c2; co4.w = (float)c3;
  *reinterpret_cast<float4*>(coords_out + n*4) = co4;
  int sh = 2 - stage[0];
  int s1 = c1 >> sh, s2 = c2 >> sh, s3 = c3 >> sh;
  scn[n*3+0] = s1; scn[n*3+1] = s2; scn[n*3+2] = s3;
  grid[(s1*GS + s2)*GS + s3] = n;

  float vs = vsz[0];
  float wx = (float)c1*vs + origin[0];
  float wy = (float)c2*vs + origin[1];
  float wz = (float)c3*vs + origin[2];
  float den = 0.f;
  #pragma unroll 1
  for (int v = 0; v < VN; ++v){
    const float* P = KR + v*12;
    float ix = P[0]*wx + P[1]*wy + P[2]*wz + P[3];
    float iy = P[4]*wx + P[5]*wy + P[6]*wz + P[7];
    float iz = P[8]*wx + P[9]*wy + P[10]*wz + P[11];
    float rz = 1.f/iz;
    float gx = 2.f*(ix*rz)/159.f - 1.f;
    float gy = 2.f*(iy*rz)/119.f - 1.f;
    bool ok = (fabsf(gx) <= 1.f) && (fabsf(gy) <= 1.f) && (iz > 0.f);
    float px = ok ? (gx + 1.f)*0.5f*79.f : 0.f;
    float py = ok ? (gy + 1.f)*0.5f*59.f : 0.f;
    float x0f = floorf(px), y0f = floorf(py);
    float fx = px - x0f, fy = py - y0f;
    int idx = (int)y0f*80 + (int)x0f;
    float mf = ok ? 1.f : 0.f;
    float w00 = (1.f-fx)*(1.f-fy)*mf, w01 = fx*(1.f-fy)*mf;
    float w10 = (1.f-fx)*fy*mf;
    // packed: .x = idx(13b) | ok<<15 | w10(bf16)<<16 ; .y = w00 | w01<<16
    uint2 s;
    s.x = (unsigned)idx | (ok ? 0x8000u : 0u) | ((unsigned)f2b(w10) << 16);
    s.y = (unsigned)f2b(w00) | ((unsigned)f2b(w01) << 16);
    samp[(size_t)v*NVOX + n] = s;
    den += mf;
  }
  cnt[n] = den;
}

// ---- merged: f1 reg conv (169) + f4 LDS (720) + f2 LDS (675) ----
__global__ __launch_bounds__(256) void k_heads(
    const ushort* nhwc1, const ushort* wf1, const float* b_f1, ushort* t1,
    const ushort* nhwc2, const ushort* wf2, const float* b_f2, ushort* fcat,
    const ushort* nhwc4, const ushort* wf4, const float* b_f4, ushort* t4){
  __shared__ ushort lds[18*18*36];
  int bid = blockIdx.x;
  int tid = threadIdx.x;
  if (bid < 169){ conv_dev<3,5,9,1>(nhwc1, wf1, b_f1, t1, 30, 40, 10800, 80, 80, 0, nullptr, bid, tid); return; }
  bid -= 169;
  if (bid < 720){ conv_lds_dev<16,2,1>(nhwc4, wf4, b_f4, t4, 120, 160, 24, 24, 0, nullptr, lds, bid, tid); return; }
  bid -= 720;
  if (bid < 675){ conv_lds_dev<4,3,2>(nhwc2, wf2, b_f2, fcat, 60, 80, 40, 160, 80, nullptr, lds, bid, tid); }
}

// ---- merged: resize+pool+padzero (5063) + slice-split nbr build (2048) ----
__global__ __launch_bounds__(256) void k_respool_nbr(
    const ushort* __restrict__ t1, const ushort* __restrict__ t4, ushort* __restrict__ fc,
    const int* __restrict__ scn, const int* __restrict__ grid,
    int* __restrict__ nbr, unsigned* __restrict__ gmask16){
  __shared__ unsigned m16[4];
  int bid = blockIdx.x;
  int tidx = threadIdx.x;
  if (bid < 5063){
    int tid = bid*256 + tidx;
    if (tid < 864000){
      int c4 = tid % 20;
      int x  = (tid / 20) % 80;
      int y  = (tid / 1600) % 60;
      int v  = tid / 96000;
      int c = c4*4;
      int ky = y >> 1; int y0, y1; float wy0, wy1;
      if ((y & 1) == 0){ y0 = ky-1; y1 = ky; wy0 = 0.25f; wy1 = 0.75f; if (y0 < 0){ y0 = 0; wy0 = 0.f; wy1 = 1.f; } }
      else             { y0 = ky; y1 = ky+1; wy0 = 0.75f; wy1 = 0.25f; if (y1 > 29){ y1 = 29; wy1 = 0.f; wy0 = 1.f; } }
      int kx = x >> 1; int x0, x1; float wx0, wx1;
      if ((x & 1) == 0){ x0 = kx-1; x1 = kx; wx0 = 0.25f; wx1 = 0.75f; if (x0 < 0){ x0 = 0; wx0 = 0.f; wx1 = 1.f; } }
      else             { x0 = kx; x1 = kx+1; wx0 = 0.75f; wx1 = 0.25f; if (x1 > 39){ x1 = 39; wx1 = 0.f; wx0 = 1.f; } }
      float4 a00 = ld4b(t1 + ((size_t)(v*30 + y0)*40 + x0)*80 + c);
      float4 a01 = ld4b(t1 + ((size_t)(v*30 + y0)*40 + x1)*80 + c);
      float4 a10 = ld4b(t1 + ((size_t)(v*30 + y1)*40 + x0)*80 + c);
      float4 a11 = ld4b(t1 + ((size_t)(v*30 + y1)*40 + x1)*80 + c);
      float w00 = wy0*wx0, w01 = wy0*wx1, w10 = wy1*wx0, w11 = wy1*wx1;
      float4 r;
      r.x = w00*a00.x + w01*a01.x + w10*a10.x + w11*a11.x;
      r.y = w00*a00.y + w01*a01.y + w10*a10.y + w11*a11.y;
      r.z = w00*a00.z + w01*a01.z + w10*a10.z + w11*a11.z;
      r.w = w00*a00.w + w01*a01.w + w10*a10.w + w11*a11.w;
      st4b(fc + ((size_t)(v*60 + y)*80 + x)*160 + c, r);
      return;
    }
    int t = tid - 864000;
    if (t >= 432000) return;
    int c4 = t % 10;
    int x  = (t / 10) % 80;
    int y  = (t / 800) % 60;
    int v  = t / 48000;
    if (c4 < 6){
      int c = c4*4;
      const ushort* b0 = t4 + ((size_t)(v*120 + 2*y)*160 + 2*x)*24 + c;
      float4 a = ld4b(b0), b = ld4b(b0 + 24), cc = ld4b(b0 + 160*24), d = ld4b(b0 + 160*24 + 24);
      float4 r;
      r.x = 0.25f*(a.x + b.x + cc.x + d.x);
      r.y = 0.25f*(a.y + b.y + cc.y + d.y);
      r.z = 0.25f*(a.z + b.z + cc.z + d.z);
      r.w = 0.25f*(a.w + b.w + cc.w + d.w);
      st4b(fc + ((size_t)(v*60 + y)*80 + x)*160 + 120 + c, r);
    } else {
      float4 zz = {0.f,0.f,0.f,0.f};
      st4b(fc + ((size_t)(v*60 + y)*80 + x)*160 + 144 + (c4-6)*4, zz);
    }
    return;
  }
  bid -= 5063;
  if (tidx < 4) m16[tidx] = 0;
  __syncthreads();
  int vb = bid*64;
  int lane = tidx & 63;
  int wv = tidx >> 6;
  int n = vb + lane;
  int sx = scn[n*3+0], sy = scn[n*3+1], sz = scn[n*3+2];
  int k0 = wv*7;
  int k1 = min(27, k0 + 7);
  unsigned msk = 0;
  #pragma unroll 1
  for (int k = k0; k < k1; ++k){
    int dx = k/9 - 1, dy = (k/3)%3 - 1, dz = k%3 - 1;
    int nx = sx+dx, ny = sy+dy, nz = sz+dz;
    int idx = -1;
    if (((unsigned)nx < 96u) && ((unsigned)ny < 96u) && ((unsigned)nz < 96u))
      idx = grid[(nx*GS + ny)*GS + nz];
    nbr[(size_t)k*NVOX + n] = idx;
    unsigned long long b = __ballot(idx >= 0);
    unsigned sub = (unsigned)((b >> ((lane >> 4)*16)) & 0xFFFFull);
    if (sub) msk |= (1u << k);
  }
  if ((lane & 15) == 0 && msk) atomicOr(&m16[lane >> 4], msk);
  __syncthreads();
  if (tidx < 4) gmask16[(vb >> 4) + tidx] = m16[tidx];
}

// ---- sampling from packed table + masked mean/var + bn0 ----
__global__ __launch_bounds__(256) void k_sample(
    const ushort* __restrict__ fuse, const uint2* __restrict__ samp,
    const float* __restrict__ cnt, const float* __restrict__ bn0g,
    const float* __restrict__ bn0b, ushort* __restrict__ F0){
  int tid = blockIdx.x*256 + threadIdx.x;
  int vox = tid >> 3;
  int c4 = tid & 7;
  int c = c4*4;
  uint2 svv[VN];
  #pragma unroll
  for (int v = 0; v < VN; ++v) svv[v] = samp[(size_t)v*NVOX + vox];
  float s0=0.f,s1=0.f,s2=0.f,s3=0.f;
  float q0=0.f,q1=0.f,q2=0.f,q3=0.f;
  #pragma unroll
  for (int v = 0; v < VN; ++v){
    uint2 sv = svv[v];
    int idx = (int)(sv.x & 0x7FFFu);
    float mf = (sv.x & 0x8000u) ? 1.f : 0.f;
    float w10 = bhi(sv.x);
    float w00 = blo(sv.y), w01 = bhi(sv.y);
    float w11 = mf - w00 - w01 - w10;
    const ushort* bp = fuse + (size_t)v*153600 + (size_t)idx*32 + c;
    float4 a00 = ld4b(bp);
    float4 a01 = ld4b(bp + 32);
    float4 a10 = ld4b(bp + 2560);
    float4 a11 = ld4b(bp + 2592);
    float g0 = w00*a00.x + w01*a01.x + w10*a10.x + w11*a11.x;
    float g1 = w00*a00.y + w01*a01.y + w10*a10.y + w11*a11.y;
    float g2 = w00*a00.z + w01*a01.z + w10*a10.z + w11*a11.z;
    float g3 = w00*a00.w + w01*a01.w + w10*a10.w + w11*a11.w;
    s0 += g0; q0 += g0*g0;
    s1 += g1; q1 += g1*g1;
    s2 += g2; q2 += g2*g2;
    s3 += g3; q3 += g3*g3;
  }
  float iden = 1.f/cnt[vox];
  float m0 = s0*iden, m1 = s1*iden, m2 = s2*iden, m3 = s3*iden;
  float4 g = ld4(bn0g + c);
  float4 b = ld4(bn0b + c);
  float4 r;
  r.x = g.x*fmaxf(q0*iden - m0*m0, 0.f)*INVS + b.x;
  r.y = g.y*fmaxf(q1*iden - m1*m1, 0.f)*INVS + b.y;
  r.z = g.z*fmaxf(q2*iden - m2*m2, 0.f)*INVS + b.z;
  r.w = g.w*fmaxf(q3*iden - m3*m3, 0.f)*INVS + b.w;
  st4b(F0 + (size_t)vox*32 + c, r);
}

// ---- subm sparse conv 32->32, 16 vox/wave, batch-3 gathers (6 vmem in flight) ----
template<int MODE>
__global__ __launch_bounds__(256, 8) void k_subm_mfma(
    const ushort* __restrict__ fin, const ushort* __restrict__ w2,
    const int* __restrict__ nbr, const unsigned* __restrict__ gmask16,
    const float* __restrict__ lng, const float* __restrict__ lnb,
    ushort* __restrict__ fout){
  int lane = threadIdx.x & 63;
  int wave = threadIdx.x >> 6;
  int vb = blockIdx.x*64 + wave*16;
  int m = lane & 15;
  int q = lane >> 4;

  f32x4v acc0 = 0.f, acc1 = 0.f;
  bf16x8 zc = (short)0;
  unsigned rem = gmask16[vb >> 4];   // wave-uniform (scalar)

  // pop a batch of up to 3 slices; invalid entries get id=-1 (zero A -> no-op MFMA)
  int kk[3], id[3];
  int npop = 0;
  #pragma unroll
  for (int j = 0; j < 3; ++j){
    bool v = rem != 0;
    int k = 0;
    if (v){ k = __ffs(rem) - 1; rem &= rem - 1; ++npop; }
    kk[j] = k;
    id[j] = v ? nbr[(size_t)k*NVOX + vb + m] : -1;
  }

  while (npop > 0){
    // 3 gathers issued back-to-back (independent)
    bf16x8 A[3];
    #pragma unroll
    for (int j = 0; j < 3; ++j){
      bf16x8 a = *(const bf16x8*)(fin + (size_t)(id[j] < 0 ? 0 : id[j])*32 + q*8);
      A[j] = (id[j] < 0) ? zc : a;
    }
    // pop next batch ids while gathers are in flight
    int nk[3], nid[3];
    int nnp = 0;
    #pragma unroll
    for (int j = 0; j < 3; ++j){
      bool v = rem != 0;
      int k = 0;
      if (v){ k = __ffs(rem) - 1; rem &= rem - 1; ++nnp; }
      nk[j] = k;
      nid[j] = v ? nbr[(size_t)k*NVOX + vb + m] : -1;
    }
    // weights + MFMAs (invalid slices: A=0 so contribution is 0)
    #pragma unroll
    for (int j = 0; j < 3; ++j){
      bf16x8 b0 = *(const bf16x8*)(w2 + (size_t)(kk[j]*32 + m)*32 + q*8);
      bf16x8 b1 = *(const bf16x8*)(w2 + (size_t)(kk[j]*32 + 16 + m)*32 + q*8);
      acc0 = __builtin_amdgcn_mfma_f32_16x16x32_bf16(A[j], b0, acc0, 0, 0, 0);
      acc1 = __builtin_amdgcn_mfma_f32_16x16x32_bf16(A[j], b1, acc1, 0, 0, 0);
    }
    #pragma unroll
    for (int j = 0; j < 3; ++j){ kk[j] = nk[j]; id[j] = nid[j]; }
    npop = nnp;
  }

  int ch0 = m, ch1 = 16 + m;
  float g0 = 0.f, g1 = 0.f, bb0 = 0.f, bb1 = 0.f;
  if (MODE == 1){ g0 = lng[ch0]; g1 = lng[ch1]; bb0 = lnb[ch0]; bb1 = lnb[ch1]; }
  #pragma unroll
  for (int r = 0; r < 4; ++r){
    int vox = vb + q*4 + r;
    float x0 = fmaxf(acc0[r], 0.f);
    float x1 = fmaxf(acc1[r], 0.f);
    if (MODE == 1){
      x0 += b2f(fin[(size_t)vox*32 + ch0]);
      x1 += b2f(fin[(size_t)vox*32 + ch1]);
      float s = x0 + x1;
      s += __shfl_xor(s, 1, 16);
      s += __shfl_xor(s, 2, 16);
      s += __shfl_xor(s, 4, 16);
      s += __shfl_xor(s, 8, 16);
      float mean = s * (1.f/32.f);
      float d0 = x0 - mean, d1 = x1 - mean;
      float v2 = d0*d0 + d1*d1;
      v2 += __shfl_xor(v2, 1, 16);
      v2 += __shfl_xor(v2, 2, 16);
      v2 += __shfl_xor(v2, 4, 16);
      v2 += __shfl_xor(v2, 8, 16);
      float rs = 1.f / sqrtf(v2*(1.f/32.f) + 1e-5f);
      x0 = d0*rs*g0 + bb0;
      x1 = d1*rs*g1 + bb1;
    }
    fout[(size_t)vox*32 + ch0] = f2b(x0);
    fout[(size_t)vox*32 + ch1] = f2b(x1);
  }
}

// ---- final subm 32->1 + bn, idx prefetch ----
__global__ __launch_bounds__(256) void k_s4(
    const ushort* __restrict__ fin, const float* __restrict__ w4,
    const int* __restrict__ nbr, const unsigned* __restrict__ gmask16,
    const float* __restrict__ bn4g, const float* __restrict__ bn4b,
    float* __restrict__ occ){
  int n = blockIdx.x*256 + threadIdx.x;
  if (n >= NVOX) return;
  unsigned rem = gmask16[n >> 4];
  float acc = 0.f;
  int k = -1, idx = -1;
  if (rem){ k = __ffs(rem) - 1; rem &= rem - 1; idx = nbr[(size_t)k*NVOX + n]; }
  while (k >= 0){
    int k2 = -1, idx2 = -1;
    if (rem){ k2 = __ffs(rem) - 1; rem &= rem - 1; idx2 = nbr[(size_t)k2*NVOX + n]; }
    if (idx >= 0){
      const uint4* r4 = (const uint4*)(fin + (size_t)idx*32);
      const float* wk = w4 + k*32;
      #pragma unroll
      for (int u = 0; u < 4; ++u){
        uint4 d = r4[u];
        const float* w8 = wk + u*8;
        acc += blo(d.x)*w8[0] + bhi(d.x)*w8[1];
        acc += blo(d.y)*w8[2] + bhi(d.y)*w8[3];
        acc += blo(d.z)*w8[4] + bhi(d.z)*w8[5];
        acc += blo(d.w)*w8[6] + bhi(d.w)*w8[7];
      }
    }
    k = k2; idx = idx2;
  }
  occ[n] = bn4g[0]*acc*INVS + bn4b[0];
}

extern "C" void kernel_launch(void* const* d_in, const int* in_sizes, int n_in,
                              void* d_out, int out_size, void* d_ws, size_t ws_size,
                              hipStream_t stream){
  const float* feats1 = (const float*)d_in[0];
  const float* feats2 = (const float*)d_in[1];
  const float* feats4 = (const float*)d_in[2];
  const int*   coords = (const int*)d_in[3];
  const float* origin = (const float*)d_in[4];
  const float* vsz    = (const float*)d_in[5];
  const float* KR     = (const float*)d_in[6];
  const float* w_f1 = (const float*)d_in[7];  const float* b_f1 = (const float*)d_in[8];
  const float* w_f2 = (const float*)d_in[9];  const float* b_f2 = (const float*)d_in[10];
  const float* w_f4 = (const float*)d_in[11]; const float* b_f4 = (const float*)d_in[12];
  const float* w_dn = (const float*)d_in[13]; const float* b_dn = (const float*)d_in[14];
  const float* w_p[4] = {(const float*)d_in[15], (const float*)d_in[17],
                         (const float*)d_in[19], (const float*)d_in[21]};
  const float* b_p[4] = {(const float*)d_in[16], (const float*)d_in[18],
                         (const float*)d_in[20], (const float*)d_in[22]};
  const float* bn0g = (const float*)d_in[23]; const float* bn0b = (const float*)d_in[24];
  const float* w_elan = (const float*)d_in[25];
  const float* w_s1 = (const float*)d_in[26]; const float* ln1g = (const float*)d_in[27]; const float* ln1b = (const float*)d_in[28];
  const float* w_s2 = (const float*)d_in[29]; const float* ln2g = (const float*)d_in[30]; const float* ln2b = (const float*)d_in[31];
  const float* w_s3 = (const float*)d_in[32]; const float* ln3g = (const float*)d_in[33]; const float* ln3b = (const float*)d_in[34];
  const float* w_s4 = (const float*)d_in[35]; const float* bn4g = (const float*)d_in[36]; const float* bn4b = (const float*)d_in[37];
  const int* stage  = (const int*)d_in[38];
  float* out = (float*)d_out;
  char* base = (char*)d_ws;

  size_t off = 0;
  auto alloc = [&](size_t bytes)->char*{ char* p = base + off; off += (bytes + 255) & ~(size_t)255; return p; };
  ushort* nhwc1 = (ushort*)alloc((size_t)9*30*40*96*2);
  ushort* nhwc2 = (ushort*)alloc((size_t)9*60*80*64*2);
  ushort* nhwc4 = (ushort*)alloc((size_t)9*120*160*32*2);
  ushort* t1    = (ushort*)alloc((size_t)9*30*40*80*2);
  ushort* t4    = (ushort*)alloc((size_t)9*120*160*24*2);
  ushort* fcat  = (ushort*)alloc((size_t)9*60*80*160*2);
  ushort* A     = (ushort*)alloc((size_t)9*60*80*32*2);
  ushort* B     = (ushort*)alloc((size_t)9*60*80*32*2);
  ushort* Fb0   = (ushort*)alloc((size_t)NVOX*32*2);
  ushort* Fb1   = (ushort*)alloc((size_t)NVOX*32*2);
  int*    nbr   = (int*)alloc((size_t)27*NVOX*4);
  int*    grid  = (int*)alloc((size_t)GS*GS*GS*4);
  int*    scn   = (int*)alloc((size_t)NVOX*3*4);
  unsigned* gmask16 = (unsigned*)alloc((size_t)(NVOX/16)*4);
  ushort* wf1   = (ushort*)alloc(9*3*80*32*2);
  ushort* wf2   = (ushort*)alloc(9*2*48*32*2);
  ushort* wf4   = (ushort*)alloc(9*1*32*32*2);
  ushort* wdn   = (ushort*)alloc(1*5*32*32*2);
  ushort* wp0   = (ushort*)alloc(9*1*32*32*2);
  ushort* wp1   = (ushort*)alloc(9*1*32*32*2);
  ushort* wp2   = (ushort*)alloc(9*1*32*32*2);
  ushort* wp3   = (ushort*)alloc(9*1*32*32*2);
  ushort* w2e   = (ushort*)alloc(27*1024*2);
  ushort* w2s1  = (ushort*)alloc(27*1024*2);
  ushort* w2s2  = (ushort*)alloc(27*1024*2);
  ushort* w2s3  = (ushort*)alloc(27*1024*2);
  uint2* samp = (uint2*)alloc((size_t)VN*NVOX*8);  // packed, 9.4 MB

  auto nb = [](int total){ return (total + 255)/256; };

  // 1. mega prep
  k_prep<<<8012,256,0,stream>>>(
      w_f1, w_f2, w_f4, w_dn, w_p[0], w_p[1], w_p[2], w_p[3],
      w_elan, w_s1, w_s2, w_s3,
      wf1, wf2, wf4, wdn, wp0, wp1, wp2, wp3, w2e, w2s1, w2s2, w2s3, grid,
      feats1, feats2, feats4, nhwc1, nhwc2, nhwc4);

  // 2. standalone scatter (R6-exact codegen; measured flip-free)
  k_scatter<<<nb(NVOX),256,0,stream>>>(coords, stage, grid, scn, out + NVOX,
                                       origin, vsz, KR, samp, out + 5*NVOX);

  // 3. head convs (f1 reg, f4 LDS, f2 LDS)
  k_heads<<<169 + 720 + 675,256,0,stream>>>(
      nhwc1, wf1, b_f1, t1,
      nhwc2, wf2, b_f2, fcat,
      nhwc4, wf4, b_f4, t4);

  // 4. respool + nbr build
  k_respool_nbr<<<5063 + 2048,256,0,stream>>>(t1, t4, fcat, scn, grid, nbr, gmask16);

  // 5-9. down conv (1x1 reg) + 4 LDS-tiled residual convs
  k_conv_mfma<5,2,1,1><<<675,256,0,stream>>>(fcat, wdn, b_dn, A, 60, 80, 43200, 32, 32, 0, nullptr);
  k_conv_lds4<<<675,256,0,stream>>>(A, wp0, b_p[0], B, A);
  k_conv_lds4<<<675,256,0,stream>>>(B, wp1, b_p[1], A, B);
  k_conv_lds4<<<675,256,0,stream>>>(A, wp2, b_p[2], B, A);
  k_conv_lds4<<<675,256,0,stream>>>(B, wp3, b_p[3], A, B);

  // 10. sampling -> F0
  k_sample<<<NVOX/32,256,0,stream>>>(A, samp, out + 5*NVOX, bn0g, bn0b, Fb0);

  // 11-14. sparse conv stack (batch-3 gather pipeline)
  k_subm_mfma<0><<<NVOX/64,256,0,stream>>>(Fb0, w2e,  nbr, gmask16, nullptr, nullptr, Fb1);
  k_subm_mfma<1><<<NVOX/64,256,0,stream>>>(Fb1, w2s1, nbr, gmask16, ln1g, ln1b, Fb0);
  k_subm_mfma<1><<<NVOX/64,256,0,stream>>>(Fb0, w2s2, nbr, gmask16, ln2g, ln2b, Fb1);
  k_subm_mfma<1><<<NVOX/64,256,0,stream>>>(Fb1, w2s3, nbr, gmask16, ln3g, ln3b, Fb0);

  // 15. final head
  k_s4<<<nb(NVOX),256,0,stream>>>(Fb0, w_s4, nbr, gmask16, bn4g, bn4b, out);
}